// Round 3
// baseline (697.002 us; speedup 1.0000x reference)
//
#include <hip/hip_runtime.h>
#include <hip/hip_bf16.h>

typedef __attribute__((ext_vector_type(8))) short s8v;
typedef __attribute__((ext_vector_type(4))) short s4v;
typedef __attribute__((ext_vector_type(4))) float f4v;

#define MFMA32(A,B,C) __builtin_amdgcn_mfma_f32_16x16x32_bf16(A,B,C,0,0,0)
#define MFMA16(A,B,C) __builtin_amdgcn_mfma_f32_16x16x16bf16_1k(A,B,C,0,0,0)

__device__ __forceinline__ unsigned short f2bf(float f){
  unsigned int u = __float_as_uint(f);
  u += 0x7FFFu + ((u>>16)&1u);
  return (unsigned short)(u>>16);
}
__device__ __forceinline__ float bf2f(unsigned short s){
  return __uint_as_float(((unsigned int)s)<<16);
}
// packed f32x4 -> bf16x4 via v_cvt_pk_bf16_f32 (RNE, same rounding as f2bf)
__device__ __forceinline__ s4v pack4(f4v v){
  float2 lo; lo.x=v[0]; lo.y=v[1];
  float2 hi; hi.x=v[2]; hi.y=v[3];
  __hip_bfloat162 a = __float22bfloat162_rn(lo);
  __hip_bfloat162 b = __float22bfloat162_rn(hi);
  union{ s4v s; unsigned int u[2]; } r;
  __builtin_memcpy(&r.u[0], &a, 4);
  __builtin_memcpy(&r.u[1], &b, 4);
  return r.s;
}

// log2(e)/8  (fold the 1/sqrt(dh)=1/8 score scale into exp2)
#define EXPC 0.18033688011112042f

// lgkm-only barrier: LDS ordering without draining vmcnt.
#define BARRIER() do{                                        \
  asm volatile("s_waitcnt lgkmcnt(0)" ::: "memory");         \
  __builtin_amdgcn_s_barrier();                              \
  asm volatile("" ::: "memory");                             \
}while(0)

// ---------------------------------------------------------------------------
// K0: Wo' [o][h*64+j] = Wo[o][j*16+h], bf16
// ---------------------------------------------------------------------------
__global__ void pack_wo(const float* __restrict__ wo, unsigned short* __restrict__ wop){
  int idx = blockIdx.x*256 + threadIdx.x;
  if(idx >= 1024*1024) return;
  int o = idx >> 10, r = idx & 1023, h = r >> 6, j = r & 63;
  wop[idx] = f2bf(wo[o*1024 + j*16 + h]);
}

// ---------------------------------------------------------------------------
// K1: projections. C[m,n] = sum_k A[m,k] * W[n,k] + bias[n]
//   z=0: KEY  -> kh[b][h][s][j]                      (j = n>>4, h = n&15)
//   z=1: QUERY-> qh[b][h][s][j]
//   z=2: VALUE-> vt[b][h][it=s>>4][j][i16=s&15]      (i-tile-major for attn staging)
// Epilogue vectorized: 16 x 8B packed stores per thread (was 64 scalar u16).
// ---------------------------------------------------------------------------
__global__ __launch_bounds__(256) void proj_gemm(
    const float* __restrict__ KEY, const float* __restrict__ VALUE, const float* __restrict__ QUERY,
    const float* __restrict__ Wk, const float* __restrict__ bk,
    const float* __restrict__ Wq, const float* __restrict__ bq,
    const float* __restrict__ Wv, const float* __restrict__ bv,
    unsigned short* __restrict__ kh, unsigned short* __restrict__ qh,
    unsigned short* __restrict__ vt)
{
  __shared__ short As[128*64];
  __shared__ short Bs[128*64];
  const int t = threadIdx.x;
  const int z = blockIdx.z;
  const float* A; const float* W; const float* bias;
  if(z==0){A=KEY;   W=Wk; bias=bk;}
  else if(z==1){A=QUERY; W=Wq; bias=bq;}
  else {A=VALUE; W=Wv; bias=bv;}
  const int m0 = blockIdx.x*128, n0 = blockIdx.y*128;
  const int l = t&63, w = t>>6;
  const int wm = (w>>1)*64, wn = (w&1)*64;
  const int row16 = l&15, quad = l>>4;
  f4v acc[4][4];
  #pragma unroll
  for(int i=0;i<4;i++)
    #pragma unroll
    for(int j=0;j<4;j++) acc[i][j] = (f4v){0.f,0.f,0.f,0.f};

  const int sr = t>>4, sc = t&15;
  for(int k0=0;k0<1024;k0+=64){
    #pragma unroll
    for(int p=0;p<8;p++){
      float4 av = *(const float4*)&A[(size_t)(m0 + p*16 + sr)*1024 + k0 + sc*4];
      float4 bvv= *(const float4*)&W[(size_t)(n0 + p*16 + sr)*1024 + k0 + sc*4];
      *(s4v*)&As[(p*16+sr)*64 + sc*4] = pack4((f4v){av.x,av.y,av.z,av.w});
      *(s4v*)&Bs[(p*16+sr)*64 + sc*4] = pack4((f4v){bvv.x,bvv.y,bvv.z,bvv.w});
    }
    __syncthreads();
    #pragma unroll
    for(int kk=0; kk<64; kk+=32){
      s8v af[4], bf[4];
      #pragma unroll
      for(int mt=0;mt<4;mt++) af[mt] = *(const s8v*)&As[(wm+mt*16+row16)*64 + kk + quad*8];
      #pragma unroll
      for(int nt=0;nt<4;nt++) bf[nt] = *(const s8v*)&Bs[(wn+nt*16+row16)*64 + kk + quad*8];
      #pragma unroll
      for(int mt=0;mt<4;mt++)
        #pragma unroll
        for(int nt=0;nt<4;nt++)
          acc[mt][nt] = MFMA32(af[mt], bf[nt], acc[mt][nt]);
    }
    __syncthreads();
  }

  // epilogue: h = n&15 = row16 for every nt; j = jb + nt (4 consecutive)
  const int jb = (n0+wn)>>4;
  const float bv0 = bias[n0+wn+ 0+row16];
  const float bv1 = bias[n0+wn+16+row16];
  const float bv2 = bias[n0+wn+32+row16];
  const float bv3 = bias[n0+wn+48+row16];
  if(z==2){
    #pragma unroll
    for(int mt=0;mt<4;mt++){
      const int m = m0+wm+mt*16;           // 16-aligned: it constant over quad,r
      const int bb=m>>11, ss=m&2047, it=ss>>4;
      const size_t base = (((size_t)(bb*16+row16))*128 + it)*64;
      #pragma unroll
      for(int nt=0;nt<4;nt++){
        const float bn = (nt==0)?bv0:(nt==1)?bv1:(nt==2)?bv2:bv3;
        f4v vals = {acc[mt][nt][0]+bn, acc[mt][nt][1]+bn,
                    acc[mt][nt][2]+bn, acc[mt][nt][3]+bn};
        *(s4v*)&vt[(base + jb+nt)*16 + quad*4] = pack4(vals);
      }
    }
  } else {
    unsigned short* dst = (z==0)? kh : qh;
    #pragma unroll
    for(int mt=0;mt<4;mt++){
      #pragma unroll
      for(int r=0;r<4;r++){
        const int m = m0+wm+mt*16+quad*4+r;
        const int bb=m>>11, ss=m&2047;
        f4v vals = {acc[mt][0][r]+bv0, acc[mt][1][r]+bv1,
                    acc[mt][2][r]+bv2, acc[mt][3][r]+bv3};
        *(s4v*)&dst[((size_t)(bb*16+row16)*2048 + ss)*64 + jb] = pack4(vals);
      }
    }
  }
}

// ---------------------------------------------------------------------------
// K2: fused attention, v3 (i16 tiles, 32 iters, 72 KiB LDS -> 2 blocks/CU).
//   - Ks[256 rows=h*16+i][64 j], b128-slot XOR swizzle (slot ^= row&7):
//     reads AND writes capacity-optimal per 32-lane phase.
//   - Vs[1024 rows=h*64+j][16 i], b64-slot XOR swizzle (slot ^= row&3):
//     2 lanes/bank-pair per phase (was 8-way on 16 banks).
//   - vt global is i-tile-major: staging = linear 16B units, fully coalesced.
//   - K and V prefetch issued in the OPPOSITE epoch from their ds_write:
//     ~full-iteration flight; no vmcnt(0) drain in the loop.
//   - dpart (head-softmax partial denominators) down to 8 KiB.
// ---------------------------------------------------------------------------
__global__ __launch_bounds__(512,4) void fused_attn(
    const unsigned short* __restrict__ kh, const unsigned short* __restrict__ qh,
    const unsigned short* __restrict__ vt, unsigned short* __restrict__ opart)
{
  __shared__ unsigned short Ks[256*64];    // 32 KB
  __shared__ unsigned short Vs[1024*16];   // 32 KB
  __shared__ f4v dpart[2][4][64];          //  8 KB

  const int t=threadIdx.x, l=t&63, w=t>>6;
  const int qg=w>>2, hg=w&3;
  const int row16=l&15, quad=l>>4;
  const int bid=blockIdx.x;
  const int combo=bid&7, qb=bid>>3;
  const int ih=combo&3, b=combo>>2;
  const int q0=qb*32+qg*16, h0=hg*4;
  const int ibase=ih*512;

  // Q fragments (global, once)
  s8v qf[4][2];
  #pragma unroll
  for(int hh=0;hh<4;hh++){
    const unsigned short* qp=&qh[(size_t)((b*16+h0+hh)*2048 + q0+row16)*64];
    qf[hh][0]=*(const s8v*)&qp[quad*8];
    qf[hh][1]=*(const s8v*)&qp[32+quad*8];
  }

  // K staging: 2048 16B-units = 256 rows x 8 slots; 4 units/thread
  const int ksl=t&7;
  const unsigned short* kp[4]; int kw[4];
  #pragma unroll
  for(int p=0;p<4;p++){
    const int urow=p*64+(t>>3), h=urow>>4, i=urow&15;
    kp[p]=&kh[((size_t)(b*16+h)*2048 + ibase + i)*64 + ksl*8];
    kw[p]=urow*64 + ((ksl^(urow&7))<<3);
  }
  // V staging: 2048 16B-units = 1024 rows x 2 halves; 4 units/thread
  const int half=t&1;
  const unsigned short* vp[4]; int vw0[4], vw1[4];
  #pragma unroll
  for(int p=0;p<4;p++){
    const int row=p*256+(t>>1), h=row>>6, j=row&63;
    vp[p]=&vt[((((size_t)(b*16+h))*128 + ih*32)*64 + j)*16 + half*8];
    vw0[p]=row*16 + (((2*half+0)^(row&3))<<2);
    vw1[p]=row*16 + (((2*half+1)^(row&3))<<2);
  }

  f4v o[4][4];
  #pragma unroll
  for(int i=0;i<4;i++)
    #pragma unroll
    for(int j=0;j<4;j++) o[i][j]=(f4v){0.f,0.f,0.f,0.f};

  s8v kreg[4], vtmp[4];
  // prologue: K(0) staged; K(1) and V(0) in flight
  #pragma unroll
  for(int p=0;p<4;p++) kreg[p]=*(const s8v*)(kp[p]);
  #pragma unroll
  for(int p=0;p<4;p++) vtmp[p]=*(const s8v*)(vp[p]);
  #pragma unroll
  for(int p=0;p<4;p++) *(s8v*)&Ks[kw[p]] = kreg[p];
  #pragma unroll
  for(int p=0;p<4;p++) kreg[p]=*(const s8v*)(kp[p] + 1024);
  BARRIER();

  const int sw0=(quad^(row16&7))<<3, sw1=((quad+4)^(row16&7))<<3;
  const int vsw=(quad^(row16&3))<<2;

  #pragma unroll 1
  for(int it=0; it<32; ++it){
    // ---------------- epoch A: write Vs=V(t); QK on Ks=K(t) ----------------
    #pragma unroll
    for(int p=0;p<4;p++){
      s4v lo={vtmp[p][0],vtmp[p][1],vtmp[p][2],vtmp[p][3]};
      s4v hi={vtmp[p][4],vtmp[p][5],vtmp[p][6],vtmp[p][7]};
      *(s4v*)&Vs[vw0[p]]=lo;
      *(s4v*)&Vs[vw1[p]]=hi;
    }
    const int tv=((it+1)&31)*1024;
    #pragma unroll
    for(int p=0;p<4;p++) vtmp[p]=*(const s8v*)(vp[p]+tv);   // V(t+1)
    f4v e0[4];
    #pragma unroll
    for(int hh=0;hh<4;hh++){
      const unsigned short* kb=&Ks[((h0+hh)*16+row16)*64];
      f4v S={0.f,0.f,0.f,0.f};
      S=MFMA32(*(const s8v*)&kb[sw0], qf[hh][0], S);
      S=MFMA32(*(const s8v*)&kb[sw1], qf[hh][1], S);
      #pragma unroll
      for(int r=0;r<4;r++) e0[hh][r]=__builtin_amdgcn_exp2f(S[r]*EXPC);
    }
    f4v d0=(e0[0]+e0[1])+(e0[2]+e0[3]);
    dpart[qg][hg][l]=d0;
    BARRIER();   // bar-mid: dpart + Vs visible; vmem stays in flight
    // ---------------- epoch B: denom, write Ks=K(t+1), PV ------------------
    f4v s0=(dpart[qg][0][l]+dpart[qg][1][l])+(dpart[qg][2][l]+dpart[qg][3][l]);
    f4v r0;
    #pragma unroll
    for(int r=0;r<4;r++) r0[r]=__builtin_amdgcn_rcpf(s0[r]);
    #pragma unroll
    for(int p=0;p<4;p++) *(s8v*)&Ks[kw[p]] = kreg[p];       // K(t+1)
    const int tk=((it+2)&31)*1024;
    #pragma unroll
    for(int p=0;p<4;p++) kreg[p]=*(const s8v*)(kp[p]+tk);   // K(t+2)
    s4v p0[4];
    #pragma unroll
    for(int hh=0;hh<4;hh++) p0[hh]=pack4(e0[hh]*r0);
    #pragma unroll
    for(int hh=0;hh<4;hh++){
      #pragma unroll
      for(int jt=0;jt<4;jt++){
        const int vrow=((h0+hh)*64+jt*16+row16)*16;
        s4v v0=*(const s4v*)&Vs[vrow + vsw];
        o[hh][jt]=MFMA16(v0, p0[hh], o[hh][jt]);
      }
    }
    BARRIER();   // bar-end: Ks(t+1) visible; Vs/dpart reads drained
  }

  // store bf16 partial: opart[ih][b][q][h*64+j]
  #pragma unroll
  for(int hh=0;hh<4;hh++)
    #pragma unroll
    for(int jt=0;jt<4;jt++)
      *(s4v*)&opart[(size_t)((ih*2+b)*2048 + q0+row16)*1024 + (h0+hh)*64 + jt*16 + quad*4]
        = pack4(o[hh][jt]);
}

// ---------------------------------------------------------------------------
// K3: reduce the 4 i-quarter partials -> out2 bf16
// ---------------------------------------------------------------------------
__global__ __launch_bounds__(256) void reduce_o(
    const unsigned short* __restrict__ op, unsigned short* __restrict__ out2)
{
  size_t e = ((size_t)blockIdx.x*256 + threadIdx.x)*8;
  s8v a = *(const s8v*)&op[e];
  s8v b = *(const s8v*)&op[(size_t)4194304 + e];
  s8v c = *(const s8v*)&op[(size_t)2*4194304 + e];
  s8v d = *(const s8v*)&op[(size_t)3*4194304 + e];
  f4v lo, hi;
  #pragma unroll
  for(int i=0;i<4;i++)
    lo[i] = (bf2f((unsigned short)a[i])+bf2f((unsigned short)b[i]))
          + (bf2f((unsigned short)c[i])+bf2f((unsigned short)d[i]));
  #pragma unroll
  for(int i=0;i<4;i++)
    hi[i] = (bf2f((unsigned short)a[i+4])+bf2f((unsigned short)b[i+4]))
          + (bf2f((unsigned short)c[i+4])+bf2f((unsigned short)d[i+4]));
  *(s4v*)&out2[e]   = pack4(lo);
  *(s4v*)&out2[e+4] = pack4(hi);
}

// ---------------------------------------------------------------------------
// K4: res[m][n] = sum_k out2[m,k]*WoP[n,k] + bo[n], fp32 out
// ---------------------------------------------------------------------------
__global__ __launch_bounds__(256) void out_gemm(
    const unsigned short* __restrict__ A, const unsigned short* __restrict__ Bm,
    const float* __restrict__ bias, float* __restrict__ out)
{
  __shared__ short As[128*64];
  __shared__ short Bs[128*64];
  const int t=threadIdx.x, l=t&63, w=t>>6;
  const int row16=l&15, quad=l>>4;
  const int m0=blockIdx.x*128, n0=blockIdx.y*128;
  const int wm=(w>>1)*64, wn=(w&1)*64;
  f4v acc[4][4];
  #pragma unroll
  for(int i=0;i<4;i++)
    #pragma unroll
    for(int j=0;j<4;j++) acc[i][j] = (f4v){0.f,0.f,0.f,0.f};

  const int sr=t>>3, sc=(t&7)*8;
  for(int k0=0;k0<1024;k0+=64){
    #pragma unroll
    for(int p=0;p<4;p++){
      *(s8v*)&As[(p*32+sr)*64 + sc] = *(const s8v*)&A [(size_t)(m0+p*32+sr)*1024 + k0 + sc];
      *(s8v*)&Bs[(p*32+sr)*64 + sc] = *(const s8v*)&Bm[(size_t)(n0+p*32+sr)*1024 + k0 + sc];
    }
    __syncthreads();
    #pragma unroll
    for(int kk=0; kk<64; kk+=32){
      s8v af[4], bf[4];
      #pragma unroll
      for(int mt=0;mt<4;mt++) af[mt] = *(const s8v*)&As[(wm+mt*16+row16)*64 + kk + quad*8];
      #pragma unroll
      for(int nt=0;nt<4;nt++) bf[nt] = *(const s8v*)&Bs[(wn+nt*16+row16)*64 + kk + quad*8];
      #pragma unroll
      for(int mt=0;mt<4;mt++)
        #pragma unroll
        for(int nt=0;nt<4;nt++)
          acc[mt][nt] = MFMA32(af[mt], bf[nt], acc[mt][nt]);
    }
    __syncthreads();
  }
  #pragma unroll
  for(int nt=0;nt<4;nt++){
    const int n = n0+wn+nt*16+row16;
    const float bias_n = bias[n];
    #pragma unroll
    for(int mt=0;mt<4;mt++)
      #pragma unroll
      for(int r=0;r<4;r++){
        const int m = m0+wm+mt*16+quad*4+r;
        out[(size_t)m*1024 + n] = acc[mt][nt][r] + bias_n;
      }
  }
}

// ---------------------------------------------------------------------------
// Workspace (56 MiB):
//   kh    @ 0        (8 MiB)  [2][16][2048][64]        dead after fused_attn
//   qh    @ 8 MiB    (8 MiB)                           dead after fused_attn
//   vt    @ 16 MiB   (8 MiB)  [2][16][128][64][16]     dead after fused_attn
//   opart @ 24 MiB   (32 MiB) [4ih][2b][2048][1024]
//   out2  @ 0        (8 MiB)  overlaps dead kh
//   wop   @ 8 MiB    (2 MiB)  overlaps dead qh (pack_wo runs after fused_attn)
// ---------------------------------------------------------------------------
extern "C" void kernel_launch(void* const* d_in, const int* in_sizes, int n_in,
                              void* d_out, int out_size, void* d_ws, size_t ws_size,
                              hipStream_t stream)
{
  const float* KEY   = (const float*)d_in[0];
  const float* VALUE = (const float*)d_in[1];
  const float* QUERY = (const float*)d_in[2];
  const float* Wk = (const float*)d_in[3];
  const float* bk = (const float*)d_in[4];
  const float* Wq = (const float*)d_in[5];
  const float* bq = (const float*)d_in[6];
  const float* Wv = (const float*)d_in[7];
  const float* bv = (const float*)d_in[8];
  const float* Wo = (const float*)d_in[9];
  const float* bo = (const float*)d_in[10];

  char* ws = (char*)d_ws;
  unsigned short* kh   = (unsigned short*)(ws);
  unsigned short* qh   = (unsigned short*)(ws +  8388608);
  unsigned short* vt   = (unsigned short*)(ws + 16777216);
  unsigned short* opart= (unsigned short*)(ws + 25165824);
  unsigned short* out2 = (unsigned short*)(ws);             // overlap kh
  unsigned short* wop  = (unsigned short*)(ws +  8388608);  // overlap qh

  proj_gemm <<<dim3(32,8,3), dim3(256), 0, stream>>>(KEY,VALUE,QUERY,Wk,bk,Wq,bq,Wv,bv,kh,qh,vt);
  fused_attn<<<dim3(512),    dim3(512), 0, stream>>>(kh,qh,vt,opart);
  pack_wo   <<<dim3(4096),   dim3(256), 0, stream>>>(Wo,wop);
  reduce_o  <<<dim3(2048),   dim3(256), 0, stream>>>(opart,out2);
  out_gemm  <<<dim3(32,8),   dim3(256), 0, stream>>>(out2,wop,bo,(float*)d_out);
}

// Round 4
// 328.226 us; speedup vs baseline: 2.1235x; 2.1235x over previous
//
#include <hip/hip_runtime.h>
#include <hip/hip_bf16.h>

typedef __attribute__((ext_vector_type(8))) short s8v;
typedef __attribute__((ext_vector_type(4))) short s4v;
typedef __attribute__((ext_vector_type(4))) float f4v;

#define MFMA32(A,B,C) __builtin_amdgcn_mfma_f32_16x16x32_bf16(A,B,C,0,0,0)
#define MFMA16(A,B,C) __builtin_amdgcn_mfma_f32_16x16x16bf16_1k(A,B,C,0,0,0)

__device__ __forceinline__ unsigned short f2bf(float f){
  unsigned int u = __float_as_uint(f);
  u += 0x7FFFu + ((u>>16)&1u);
  return (unsigned short)(u>>16);
}
__device__ __forceinline__ float bf2f(unsigned short s){
  return __uint_as_float(((unsigned int)s)<<16);
}
// packed f32x4 -> bf16x4 via v_cvt_pk_bf16_f32 (RNE, same rounding as f2bf)
__device__ __forceinline__ s4v pack4(f4v v){
  float2 lo; lo.x=v[0]; lo.y=v[1];
  float2 hi; hi.x=v[2]; hi.y=v[3];
  __hip_bfloat162 a = __float22bfloat162_rn(lo);
  __hip_bfloat162 b = __float22bfloat162_rn(hi);
  union{ s4v s; unsigned int u[2]; } r;
  __builtin_memcpy(&r.u[0], &a, 4);
  __builtin_memcpy(&r.u[1], &b, 4);
  return r.s;
}

// log2(e)/8  (fold the 1/sqrt(dh)=1/8 score scale into exp2)
#define EXPC 0.18033688011112042f

// lgkm-only barrier: LDS ordering without draining vmcnt.
#define BARRIER() do{                                        \
  asm volatile("s_waitcnt lgkmcnt(0)" ::: "memory");         \
  __builtin_amdgcn_s_barrier();                              \
  asm volatile("" ::: "memory");                             \
}while(0)

// ---------------------------------------------------------------------------
// K0: Wo' [o][h*64+j] = Wo[o][j*16+h], bf16
// ---------------------------------------------------------------------------
__global__ void pack_wo(const float* __restrict__ wo, unsigned short* __restrict__ wop){
  int idx = blockIdx.x*256 + threadIdx.x;
  if(idx >= 1024*1024) return;
  int o = idx >> 10, r = idx & 1023, h = r >> 6, j = r & 63;
  wop[idx] = f2bf(wo[o*1024 + j*16 + h]);
}

// ---------------------------------------------------------------------------
// K1: projections. C[m,n] = sum_k A[m,k] * W[n,k] + bias[n]
//   z=0: KEY  -> kh[b][h][s][j]                      (j = n>>4, h = n&15)
//   z=1: QUERY-> qh[b][h][s][j]
//   z=2: VALUE-> vt[b][h][it=s>>4][j][i16=s&15]      (i-tile-major for attn staging)
// ---------------------------------------------------------------------------
__global__ __launch_bounds__(256) void proj_gemm(
    const float* __restrict__ KEY, const float* __restrict__ VALUE, const float* __restrict__ QUERY,
    const float* __restrict__ Wk, const float* __restrict__ bk,
    const float* __restrict__ Wq, const float* __restrict__ bq,
    const float* __restrict__ Wv, const float* __restrict__ bv,
    unsigned short* __restrict__ kh, unsigned short* __restrict__ qh,
    unsigned short* __restrict__ vt)
{
  __shared__ short As[128*64];
  __shared__ short Bs[128*64];
  const int t = threadIdx.x;
  const int z = blockIdx.z;
  const float* A; const float* W; const float* bias;
  if(z==0){A=KEY;   W=Wk; bias=bk;}
  else if(z==1){A=QUERY; W=Wq; bias=bq;}
  else {A=VALUE; W=Wv; bias=bv;}
  const int m0 = blockIdx.x*128, n0 = blockIdx.y*128;
  const int l = t&63, w = t>>6;
  const int wm = (w>>1)*64, wn = (w&1)*64;
  const int row16 = l&15, quad = l>>4;
  f4v acc[4][4];
  #pragma unroll
  for(int i=0;i<4;i++)
    #pragma unroll
    for(int j=0;j<4;j++) acc[i][j] = (f4v){0.f,0.f,0.f,0.f};

  const int sr = t>>4, sc = t&15;
  for(int k0=0;k0<1024;k0+=64){
    #pragma unroll
    for(int p=0;p<8;p++){
      float4 av = *(const float4*)&A[(size_t)(m0 + p*16 + sr)*1024 + k0 + sc*4];
      float4 bvv= *(const float4*)&W[(size_t)(n0 + p*16 + sr)*1024 + k0 + sc*4];
      *(s4v*)&As[(p*16+sr)*64 + sc*4] = pack4((f4v){av.x,av.y,av.z,av.w});
      *(s4v*)&Bs[(p*16+sr)*64 + sc*4] = pack4((f4v){bvv.x,bvv.y,bvv.z,bvv.w});
    }
    __syncthreads();
    #pragma unroll
    for(int kk=0; kk<64; kk+=32){
      s8v af[4], bf[4];
      #pragma unroll
      for(int mt=0;mt<4;mt++) af[mt] = *(const s8v*)&As[(wm+mt*16+row16)*64 + kk + quad*8];
      #pragma unroll
      for(int nt=0;nt<4;nt++) bf[nt] = *(const s8v*)&Bs[(wn+nt*16+row16)*64 + kk + quad*8];
      #pragma unroll
      for(int mt=0;mt<4;mt++)
        #pragma unroll
        for(int nt=0;nt<4;nt++)
          acc[mt][nt] = MFMA32(af[mt], bf[nt], acc[mt][nt]);
    }
    __syncthreads();
  }

  // epilogue: h = n&15 = row16 for every nt; j = jb + nt (4 consecutive)
  const int jb = (n0+wn)>>4;
  const float bv0 = bias[n0+wn+ 0+row16];
  const float bv1 = bias[n0+wn+16+row16];
  const float bv2 = bias[n0+wn+32+row16];
  const float bv3 = bias[n0+wn+48+row16];
  if(z==2){
    #pragma unroll
    for(int mt=0;mt<4;mt++){
      const int m = m0+wm+mt*16;           // 16-aligned: it constant over quad,r
      const int bb=m>>11, ss=m&2047, it=ss>>4;
      const size_t base = (((size_t)(bb*16+row16))*128 + it)*64;
      #pragma unroll
      for(int nt=0;nt<4;nt++){
        const float bn = (nt==0)?bv0:(nt==1)?bv1:(nt==2)?bv2:bv3;
        f4v vals = {acc[mt][nt][0]+bn, acc[mt][nt][1]+bn,
                    acc[mt][nt][2]+bn, acc[mt][nt][3]+bn};
        *(s4v*)&vt[(base + jb+nt)*16 + quad*4] = pack4(vals);
      }
    }
  } else {
    unsigned short* dst = (z==0)? kh : qh;
    #pragma unroll
    for(int mt=0;mt<4;mt++){
      #pragma unroll
      for(int r=0;r<4;r++){
        const int m = m0+wm+mt*16+quad*4+r;
        const int bb=m>>11, ss=m&2047;
        f4v vals = {acc[mt][0][r]+bv0, acc[mt][1][r]+bv1,
                    acc[mt][2][r]+bv2, acc[mt][3][r]+bv3};
        *(s4v*)&dst[((size_t)(bb*16+row16)*2048 + ss)*64 + jb] = pack4(vals);
      }
    }
  }
}

// ---------------------------------------------------------------------------
// K2: fused attention, v4 (v3 geometry, spill-free).
//   - __launch_bounds__(512) only: VGPR free up to 256 (512-deep unified
//     file => 2 waves/SIMD still launchable). v3's (512,4) capped VGPR at
//     64 -> catastrophic scratch spill (FETCH 1.28 GB). 1 block/CU.
//   - V swizzle key fixed: (row>>2)&3 (rows r,r+4,r+8,r+12 share a bank
//     base; key must differ across them). Writes conflict-free, reads 2-way.
//   - Ks b128-slot XOR swizzle (slot ^= row&7) unchanged.
//   - K and V prefetch issued in the OPPOSITE epoch from their ds_write:
//     ~full-iteration flight; no vmcnt(0) drain in the loop.
// ---------------------------------------------------------------------------
__global__ __launch_bounds__(512) void fused_attn(
    const unsigned short* __restrict__ kh, const unsigned short* __restrict__ qh,
    const unsigned short* __restrict__ vt, unsigned short* __restrict__ opart)
{
  __shared__ unsigned short Ks[256*64];    // 32 KB
  __shared__ unsigned short Vs[1024*16];   // 32 KB
  __shared__ f4v dpart[2][4][64];          //  8 KB

  const int t=threadIdx.x, l=t&63, w=t>>6;
  const int qg=w>>2, hg=w&3;
  const int row16=l&15, quad=l>>4;
  const int bid=blockIdx.x;
  const int combo=bid&7, qb=bid>>3;
  const int ih=combo&3, b=combo>>2;
  const int q0=qb*32+qg*16, h0=hg*4;
  const int ibase=ih*512;

  // Q fragments (global, once)
  s8v qf[4][2];
  #pragma unroll
  for(int hh=0;hh<4;hh++){
    const unsigned short* qp=&qh[(size_t)((b*16+h0+hh)*2048 + q0+row16)*64];
    qf[hh][0]=*(const s8v*)&qp[quad*8];
    qf[hh][1]=*(const s8v*)&qp[32+quad*8];
  }

  // K staging: 2048 16B-units = 256 rows x 8 slots; 4 units/thread
  const int ksl=t&7;
  const unsigned short* kp[4]; int kw[4];
  #pragma unroll
  for(int p=0;p<4;p++){
    const int urow=p*64+(t>>3), h=urow>>4, i=urow&15;
    kp[p]=&kh[((size_t)(b*16+h)*2048 + ibase + i)*64 + ksl*8];
    kw[p]=urow*64 + ((ksl^(urow&7))<<3);
  }
  // V staging: 2048 16B-units = 1024 rows x 2 halves; 4 units/thread
  // key = (row>>2)&3 = (t>>3)&3 (row = p*256 + (t>>1); 256,64 ≡ 0 mod 4)
  const int half=t&1;
  const int vkey=(t>>3)&3;
  const unsigned short* vp[4]; int vw0[4], vw1[4];
  #pragma unroll
  for(int p=0;p<4;p++){
    const int row=p*256+(t>>1), h=row>>6, j=row&63;
    vp[p]=&vt[((((size_t)(b*16+h))*128 + ih*32)*64 + j)*16 + half*8];
    vw0[p]=row*16 + (((2*half+0)^vkey)<<2);
    vw1[p]=row*16 + (((2*half+1)^vkey)<<2);
  }

  f4v o[4][4];
  #pragma unroll
  for(int i=0;i<4;i++)
    #pragma unroll
    for(int j=0;j<4;j++) o[i][j]=(f4v){0.f,0.f,0.f,0.f};

  s8v kreg[4], vtmp[4];
  // prologue: K(0) staged; K(1) and V(0) in flight
  #pragma unroll
  for(int p=0;p<4;p++) kreg[p]=*(const s8v*)(kp[p]);
  #pragma unroll
  for(int p=0;p<4;p++) vtmp[p]=*(const s8v*)(vp[p]);
  #pragma unroll
  for(int p=0;p<4;p++) *(s8v*)&Ks[kw[p]] = kreg[p];
  #pragma unroll
  for(int p=0;p<4;p++) kreg[p]=*(const s8v*)(kp[p] + 1024);
  BARRIER();

  const int sw0=(quad^(row16&7))<<3, sw1=((quad+4)^(row16&7))<<3;
  const int vsw=(quad^((row16>>2)&3))<<2;   // read key matches write key

  #pragma unroll 1
  for(int it=0; it<32; ++it){
    // ---------------- epoch A: write Vs=V(t); QK on Ks=K(t) ----------------
    #pragma unroll
    for(int p=0;p<4;p++){
      s4v lo={vtmp[p][0],vtmp[p][1],vtmp[p][2],vtmp[p][3]};
      s4v hi={vtmp[p][4],vtmp[p][5],vtmp[p][6],vtmp[p][7]};
      *(s4v*)&Vs[vw0[p]]=lo;
      *(s4v*)&Vs[vw1[p]]=hi;
    }
    const int tv=((it+1)&31)*1024;
    #pragma unroll
    for(int p=0;p<4;p++) vtmp[p]=*(const s8v*)(vp[p]+tv);   // V(t+1)
    f4v e0[4];
    #pragma unroll
    for(int hh=0;hh<4;hh++){
      const unsigned short* kb=&Ks[((h0+hh)*16+row16)*64];
      f4v S={0.f,0.f,0.f,0.f};
      S=MFMA32(*(const s8v*)&kb[sw0], qf[hh][0], S);
      S=MFMA32(*(const s8v*)&kb[sw1], qf[hh][1], S);
      #pragma unroll
      for(int r=0;r<4;r++) e0[hh][r]=__builtin_amdgcn_exp2f(S[r]*EXPC);
    }
    f4v d0=(e0[0]+e0[1])+(e0[2]+e0[3]);
    dpart[qg][hg][l]=d0;
    BARRIER();   // bar-mid: dpart + Vs visible; vmem stays in flight
    // ---------------- epoch B: denom, write Ks=K(t+1), PV ------------------
    f4v s0=(dpart[qg][0][l]+dpart[qg][1][l])+(dpart[qg][2][l]+dpart[qg][3][l]);
    f4v r0;
    #pragma unroll
    for(int r=0;r<4;r++) r0[r]=__builtin_amdgcn_rcpf(s0[r]);
    #pragma unroll
    for(int p=0;p<4;p++) *(s8v*)&Ks[kw[p]] = kreg[p];       // K(t+1)
    const int tk=((it+2)&31)*1024;
    #pragma unroll
    for(int p=0;p<4;p++) kreg[p]=*(const s8v*)(kp[p]+tk);   // K(t+2)
    s4v p0[4];
    #pragma unroll
    for(int hh=0;hh<4;hh++) p0[hh]=pack4(e0[hh]*r0);
    #pragma unroll
    for(int hh=0;hh<4;hh++){
      #pragma unroll
      for(int jt=0;jt<4;jt++){
        const int vrow=((h0+hh)*64+jt*16+row16)*16;
        s4v v0=*(const s4v*)&Vs[vrow + vsw];
        o[hh][jt]=MFMA16(v0, p0[hh], o[hh][jt]);
      }
    }
    BARRIER();   // bar-end: Ks(t+1) visible; Vs/dpart reads drained
  }

  // store bf16 partial: opart[ih][b][q][h*64+j]
  #pragma unroll
  for(int hh=0;hh<4;hh++)
    #pragma unroll
    for(int jt=0;jt<4;jt++)
      *(s4v*)&opart[(size_t)((ih*2+b)*2048 + q0+row16)*1024 + (h0+hh)*64 + jt*16 + quad*4]
        = pack4(o[hh][jt]);
}

// ---------------------------------------------------------------------------
// K3: reduce the 4 i-quarter partials -> out2 bf16
// ---------------------------------------------------------------------------
__global__ __launch_bounds__(256) void reduce_o(
    const unsigned short* __restrict__ op, unsigned short* __restrict__ out2)
{
  size_t e = ((size_t)blockIdx.x*256 + threadIdx.x)*8;
  s8v a = *(const s8v*)&op[e];
  s8v b = *(const s8v*)&op[(size_t)4194304 + e];
  s8v c = *(const s8v*)&op[(size_t)2*4194304 + e];
  s8v d = *(const s8v*)&op[(size_t)3*4194304 + e];
  f4v lo, hi;
  #pragma unroll
  for(int i=0;i<4;i++)
    lo[i] = (bf2f((unsigned short)a[i])+bf2f((unsigned short)b[i]))
          + (bf2f((unsigned short)c[i])+bf2f((unsigned short)d[i]));
  #pragma unroll
  for(int i=0;i<4;i++)
    hi[i] = (bf2f((unsigned short)a[i+4])+bf2f((unsigned short)b[i+4]))
          + (bf2f((unsigned short)c[i+4])+bf2f((unsigned short)d[i+4]));
  *(s4v*)&out2[e]   = pack4(lo);
  *(s4v*)&out2[e+4] = pack4(hi);
}

// ---------------------------------------------------------------------------
// K4: res[m][n] = sum_k out2[m,k]*WoP[n,k] + bo[n], fp32 out
// ---------------------------------------------------------------------------
__global__ __launch_bounds__(256) void out_gemm(
    const unsigned short* __restrict__ A, const unsigned short* __restrict__ Bm,
    const float* __restrict__ bias, float* __restrict__ out)
{
  __shared__ short As[128*64];
  __shared__ short Bs[128*64];
  const int t=threadIdx.x, l=t&63, w=t>>6;
  const int row16=l&15, quad=l>>4;
  const int m0=blockIdx.x*128, n0=blockIdx.y*128;
  const int wm=(w>>1)*64, wn=(w&1)*64;
  f4v acc[4][4];
  #pragma unroll
  for(int i=0;i<4;i++)
    #pragma unroll
    for(int j=0;j<4;j++) acc[i][j] = (f4v){0.f,0.f,0.f,0.f};

  const int sr=t>>3, sc=(t&7)*8;
  for(int k0=0;k0<1024;k0+=64){
    #pragma unroll
    for(int p=0;p<4;p++){
      *(s8v*)&As[(p*32+sr)*64 + sc] = *(const s8v*)&A [(size_t)(m0+p*32+sr)*1024 + k0 + sc];
      *(s8v*)&Bs[(p*32+sr)*64 + sc] = *(const s8v*)&Bm[(size_t)(n0+p*32+sr)*1024 + k0 + sc];
    }
    __syncthreads();
    #pragma unroll
    for(int kk=0; kk<64; kk+=32){
      s8v af[4], bf[4];
      #pragma unroll
      for(int mt=0;mt<4;mt++) af[mt] = *(const s8v*)&As[(wm+mt*16+row16)*64 + kk + quad*8];
      #pragma unroll
      for(int nt=0;nt<4;nt++) bf[nt] = *(const s8v*)&Bs[(wn+nt*16+row16)*64 + kk + quad*8];
      #pragma unroll
      for(int mt=0;mt<4;mt++)
        #pragma unroll
        for(int nt=0;nt<4;nt++)
          acc[mt][nt] = MFMA32(af[mt], bf[nt], acc[mt][nt]);
    }
    __syncthreads();
  }
  #pragma unroll
  for(int nt=0;nt<4;nt++){
    const int n = n0+wn+nt*16+row16;
    const float bias_n = bias[n];
    #pragma unroll
    for(int mt=0;mt<4;mt++)
      #pragma unroll
      for(int r=0;r<4;r++){
        const int m = m0+wm+mt*16+quad*4+r;
        out[(size_t)m*1024 + n] = acc[mt][nt][r] + bias_n;
      }
  }
}

// ---------------------------------------------------------------------------
// Workspace (56 MiB):
//   kh    @ 0        (8 MiB)  [2][16][2048][64]        dead after fused_attn
//   qh    @ 8 MiB    (8 MiB)                           dead after fused_attn
//   vt    @ 16 MiB   (8 MiB)  [2][16][128][64][16]     dead after fused_attn
//   opart @ 24 MiB   (32 MiB) [4ih][2b][2048][1024]
//   out2  @ 0        (8 MiB)  overlaps dead kh
//   wop   @ 8 MiB    (2 MiB)  overlaps dead qh (pack_wo runs after fused_attn)
// ---------------------------------------------------------------------------
extern "C" void kernel_launch(void* const* d_in, const int* in_sizes, int n_in,
                              void* d_out, int out_size, void* d_ws, size_t ws_size,
                              hipStream_t stream)
{
  const float* KEY   = (const float*)d_in[0];
  const float* VALUE = (const float*)d_in[1];
  const float* QUERY = (const float*)d_in[2];
  const float* Wk = (const float*)d_in[3];
  const float* bk = (const float*)d_in[4];
  const float* Wq = (const float*)d_in[5];
  const float* bq = (const float*)d_in[6];
  const float* Wv = (const float*)d_in[7];
  const float* bv = (const float*)d_in[8];
  const float* Wo = (const float*)d_in[9];
  const float* bo = (const float*)d_in[10];

  char* ws = (char*)d_ws;
  unsigned short* kh   = (unsigned short*)(ws);
  unsigned short* qh   = (unsigned short*)(ws +  8388608);
  unsigned short* vt   = (unsigned short*)(ws + 16777216);
  unsigned short* opart= (unsigned short*)(ws + 25165824);
  unsigned short* out2 = (unsigned short*)(ws);             // overlap kh
  unsigned short* wop  = (unsigned short*)(ws +  8388608);  // overlap qh

  proj_gemm <<<dim3(32,8,3), dim3(256), 0, stream>>>(KEY,VALUE,QUERY,Wk,bk,Wq,bq,Wv,bv,kh,qh,vt);
  fused_attn<<<dim3(512),    dim3(512), 0, stream>>>(kh,qh,vt,opart);
  pack_wo   <<<dim3(4096),   dim3(256), 0, stream>>>(Wo,wop);
  reduce_o  <<<dim3(2048),   dim3(256), 0, stream>>>(opart,out2);
  out_gemm  <<<dim3(32,8),   dim3(256), 0, stream>>>(out2,wop,bo,(float*)d_out);
}

// Round 5
// 302.740 us; speedup vs baseline: 2.3023x; 1.0842x over previous
//
#include <hip/hip_runtime.h>
#include <hip/hip_bf16.h>

typedef __attribute__((ext_vector_type(8))) short s8v;
typedef __attribute__((ext_vector_type(4))) short s4v;
typedef __attribute__((ext_vector_type(4))) float f4v;

#define MFMA32(A,B,C) __builtin_amdgcn_mfma_f32_16x16x32_bf16(A,B,C,0,0,0)
#define MFMA16(A,B,C) __builtin_amdgcn_mfma_f32_16x16x16bf16_1k(A,B,C,0,0,0)

__device__ __forceinline__ unsigned short f2bf(float f){
  unsigned int u = __float_as_uint(f);
  u += 0x7FFFu + ((u>>16)&1u);
  return (unsigned short)(u>>16);
}
__device__ __forceinline__ float bf2f(unsigned short s){
  return __uint_as_float(((unsigned int)s)<<16);
}
// packed f32x4 -> bf16x4 via v_cvt_pk_bf16_f32 (RNE, same rounding as f2bf)
__device__ __forceinline__ s4v pack4(f4v v){
  float2 lo; lo.x=v[0]; lo.y=v[1];
  float2 hi; hi.x=v[2]; hi.y=v[3];
  __hip_bfloat162 a = __float22bfloat162_rn(lo);
  __hip_bfloat162 b = __float22bfloat162_rn(hi);
  union{ s4v s; unsigned int u[2]; } r;
  __builtin_memcpy(&r.u[0], &a, 4);
  __builtin_memcpy(&r.u[1], &b, 4);
  return r.s;
}

// log2(e)/8  (fold the 1/sqrt(dh)=1/8 score scale into exp2)
#define EXPC 0.18033688011112042f

// lgkm-only barrier: LDS ordering without draining vmcnt.
#define BARRIER() do{                                        \
  asm volatile("s_waitcnt lgkmcnt(0)" ::: "memory");         \
  __builtin_amdgcn_s_barrier();                              \
  asm volatile("" ::: "memory");                             \
}while(0)

// ---------------------------------------------------------------------------
// K-1: one-shot f32 -> bf16 conversion of the 3 activations + 3 weights.
// Removes all f32 staging + cvt from proj_gemm (halves re-read bytes, frees
// VALU). 90 MB of traffic ~= 15 us.
// grid (2048, 6); weight segments use only 512 blocks, rest exit.
// ---------------------------------------------------------------------------
__global__ __launch_bounds__(256) void conv_in(
    const float* __restrict__ KEY, const float* __restrict__ QUERY, const float* __restrict__ VALUE,
    const float* __restrict__ Wk, const float* __restrict__ Wq, const float* __restrict__ Wv,
    unsigned short* __restrict__ kb, unsigned short* __restrict__ qb,
    unsigned short* __restrict__ vb, unsigned short* __restrict__ wkb,
    unsigned short* __restrict__ wqb, unsigned short* __restrict__ wvb)
{
  const int z = blockIdx.y;
  const size_t n = (z<3)? (size_t)4194304 : (size_t)1048576;
  size_t idx = ((size_t)blockIdx.x*256 + threadIdx.x)*8;
  if(idx >= n) return;
  const float* s = (z==0)?KEY:(z==1)?QUERY:(z==2)?VALUE:(z==3)?Wk:(z==4)?Wq:Wv;
  unsigned short* d = (z==0)?kb:(z==1)?qb:(z==2)?vb:(z==3)?wkb:(z==4)?wqb:wvb;
  float4 a = *(const float4*)&s[idx];
  float4 b = *(const float4*)&s[idx+4];
  union{ s8v v; s4v h[2]; } r;
  r.h[0]=pack4((f4v){a.x,a.y,a.z,a.w});
  r.h[1]=pack4((f4v){b.x,b.y,b.z,b.w});
  *(s8v*)&d[idx]=r.v;
}

// ---------------------------------------------------------------------------
// K0: Wo' [o][h*64+j] = Wo[o][j*16+h], bf16  (runs AFTER fused_attn; wop
// overlaps the then-dead kh region)
// ---------------------------------------------------------------------------
__global__ void pack_wo(const float* __restrict__ wo, unsigned short* __restrict__ wop){
  int idx = blockIdx.x*256 + threadIdx.x;
  if(idx >= 1024*1024) return;
  int o = idx >> 10, r = idx & 1023, h = r >> 6, j = r & 63;
  wop[idx] = f2bf(wo[o*1024 + j*16 + h]);
}

// ---------------------------------------------------------------------------
// K1: projections, bf16 in / bf16 out. C[m,n] = sum_k A[m,k]*W[n,k] + bias[n]
//   z=0: kb,wkb -> kh[b][h][s][j]                  (j = n>>4, h = n&15)
//   z=1: qb,wqb -> qh[b][h][s][j]
//   z=2: vb,wvb -> vt[b][h][it=s>>4][j][i16=s&15]  (i-tile-major for attn)
// Staging = out_gemm's: 2 s8v loads + 2 ds_writes per pass, no conversion.
// ---------------------------------------------------------------------------
__global__ __launch_bounds__(256) void proj_gemm(
    const unsigned short* __restrict__ kbp, const unsigned short* __restrict__ qbp,
    const unsigned short* __restrict__ vbp,
    const unsigned short* __restrict__ wkb, const unsigned short* __restrict__ wqb,
    const unsigned short* __restrict__ wvb,
    const float* __restrict__ bk, const float* __restrict__ bq, const float* __restrict__ bv,
    unsigned short* __restrict__ kh, unsigned short* __restrict__ qh,
    unsigned short* __restrict__ vt)
{
  __shared__ short As[128*64];
  __shared__ short Bs[128*64];
  const int t = threadIdx.x;
  const int z = blockIdx.z;
  const unsigned short* A; const unsigned short* W; const float* bias;
  if(z==0){A=kbp; W=wkb; bias=bk;}
  else if(z==1){A=qbp; W=wqb; bias=bq;}
  else {A=vbp; W=wvb; bias=bv;}
  const int m0 = blockIdx.x*128, n0 = blockIdx.y*128;
  const int l = t&63, w = t>>6;
  const int wm = (w>>1)*64, wn = (w&1)*64;
  const int row16 = l&15, quad = l>>4;
  f4v acc[4][4];
  #pragma unroll
  for(int i=0;i<4;i++)
    #pragma unroll
    for(int j=0;j<4;j++) acc[i][j] = (f4v){0.f,0.f,0.f,0.f};

  const int sr=t>>3, sc=(t&7)*8;
  for(int k0=0;k0<1024;k0+=64){
    #pragma unroll
    for(int p=0;p<4;p++){
      *(s8v*)&As[(p*32+sr)*64 + sc] = *(const s8v*)&A[(size_t)(m0+p*32+sr)*1024 + k0 + sc];
      *(s8v*)&Bs[(p*32+sr)*64 + sc] = *(const s8v*)&W[(size_t)(n0+p*32+sr)*1024 + k0 + sc];
    }
    __syncthreads();
    #pragma unroll
    for(int kk=0; kk<64; kk+=32){
      s8v af[4], bf[4];
      #pragma unroll
      for(int mt=0;mt<4;mt++) af[mt] = *(const s8v*)&As[(wm+mt*16+row16)*64 + kk + quad*8];
      #pragma unroll
      for(int nt=0;nt<4;nt++) bf[nt] = *(const s8v*)&Bs[(wn+nt*16+row16)*64 + kk + quad*8];
      #pragma unroll
      for(int mt=0;mt<4;mt++)
        #pragma unroll
        for(int nt=0;nt<4;nt++)
          acc[mt][nt] = MFMA32(af[mt], bf[nt], acc[mt][nt]);
    }
    __syncthreads();
  }

  // epilogue: h = n&15 = row16 for every nt; j = jb + nt (4 consecutive)
  const int jb = (n0+wn)>>4;
  const float bv0 = bias[n0+wn+ 0+row16];
  const float bv1 = bias[n0+wn+16+row16];
  const float bv2 = bias[n0+wn+32+row16];
  const float bv3 = bias[n0+wn+48+row16];
  if(z==2){
    #pragma unroll
    for(int mt=0;mt<4;mt++){
      const int m = m0+wm+mt*16;           // 16-aligned: it constant over quad,r
      const int bb=m>>11, ss=m&2047, it=ss>>4;
      const size_t base = (((size_t)(bb*16+row16))*128 + it)*64;
      #pragma unroll
      for(int nt=0;nt<4;nt++){
        const float bn = (nt==0)?bv0:(nt==1)?bv1:(nt==2)?bv2:bv3;
        f4v vals = {acc[mt][nt][0]+bn, acc[mt][nt][1]+bn,
                    acc[mt][nt][2]+bn, acc[mt][nt][3]+bn};
        *(s4v*)&vt[(base + jb+nt)*16 + quad*4] = pack4(vals);
      }
    }
  } else {
    unsigned short* dst = (z==0)? kh : qh;
    #pragma unroll
    for(int mt=0;mt<4;mt++){
      #pragma unroll
      for(int r=0;r<4;r++){
        const int m = m0+wm+mt*16+quad*4+r;
        const int bb=m>>11, ss=m&2047;
        f4v vals = {acc[mt][0][r]+bv0, acc[mt][1][r]+bv1,
                    acc[mt][2][r]+bv2, acc[mt][3][r]+bv3};
        *(s4v*)&dst[((size_t)(bb*16+row16)*2048 + ss)*64 + jb] = pack4(vals);
      }
    }
  }
}

// ---------------------------------------------------------------------------
// K2: fused attention, v4 (unchanged from R4 winner: 113.6 us, 0 conflicts).
// ---------------------------------------------------------------------------
__global__ __launch_bounds__(512) void fused_attn(
    const unsigned short* __restrict__ kh, const unsigned short* __restrict__ qh,
    const unsigned short* __restrict__ vt, unsigned short* __restrict__ opart)
{
  __shared__ unsigned short Ks[256*64];    // 32 KB
  __shared__ unsigned short Vs[1024*16];   // 32 KB
  __shared__ f4v dpart[2][4][64];          //  8 KB

  const int t=threadIdx.x, l=t&63, w=t>>6;
  const int qg=w>>2, hg=w&3;
  const int row16=l&15, quad=l>>4;
  const int bid=blockIdx.x;
  const int combo=bid&7, qb=bid>>3;
  const int ih=combo&3, b=combo>>2;
  const int q0=qb*32+qg*16, h0=hg*4;
  const int ibase=ih*512;

  // Q fragments (global, once)
  s8v qf[4][2];
  #pragma unroll
  for(int hh=0;hh<4;hh++){
    const unsigned short* qp=&qh[(size_t)((b*16+h0+hh)*2048 + q0+row16)*64];
    qf[hh][0]=*(const s8v*)&qp[quad*8];
    qf[hh][1]=*(const s8v*)&qp[32+quad*8];
  }

  // K staging: 2048 16B-units = 256 rows x 8 slots; 4 units/thread
  const int ksl=t&7;
  const unsigned short* kp[4]; int kw[4];
  #pragma unroll
  for(int p=0;p<4;p++){
    const int urow=p*64+(t>>3), h=urow>>4, i=urow&15;
    kp[p]=&kh[((size_t)(b*16+h)*2048 + ibase + i)*64 + ksl*8];
    kw[p]=urow*64 + ((ksl^(urow&7))<<3);
  }
  // V staging: 2048 16B-units = 1024 rows x 2 halves; 4 units/thread
  // key = (row>>2)&3 = (t>>3)&3 (row = p*256 + (t>>1); 256,64 ≡ 0 mod 4)
  const int half=t&1;
  const int vkey=(t>>3)&3;
  const unsigned short* vp[4]; int vw0[4], vw1[4];
  #pragma unroll
  for(int p=0;p<4;p++){
    const int row=p*256+(t>>1), h=row>>6, j=row&63;
    vp[p]=&vt[((((size_t)(b*16+h))*128 + ih*32)*64 + j)*16 + half*8];
    vw0[p]=row*16 + (((2*half+0)^vkey)<<2);
    vw1[p]=row*16 + (((2*half+1)^vkey)<<2);
  }

  f4v o[4][4];
  #pragma unroll
  for(int i=0;i<4;i++)
    #pragma unroll
    for(int j=0;j<4;j++) o[i][j]=(f4v){0.f,0.f,0.f,0.f};

  s8v kreg[4], vtmp[4];
  // prologue: K(0) staged; K(1) and V(0) in flight
  #pragma unroll
  for(int p=0;p<4;p++) kreg[p]=*(const s8v*)(kp[p]);
  #pragma unroll
  for(int p=0;p<4;p++) vtmp[p]=*(const s8v*)(vp[p]);
  #pragma unroll
  for(int p=0;p<4;p++) *(s8v*)&Ks[kw[p]] = kreg[p];
  #pragma unroll
  for(int p=0;p<4;p++) kreg[p]=*(const s8v*)(kp[p] + 1024);
  BARRIER();

  const int sw0=(quad^(row16&7))<<3, sw1=((quad+4)^(row16&7))<<3;
  const int vsw=(quad^((row16>>2)&3))<<2;   // read key matches write key

  #pragma unroll 1
  for(int it=0; it<32; ++it){
    // ---------------- epoch A: write Vs=V(t); QK on Ks=K(t) ----------------
    #pragma unroll
    for(int p=0;p<4;p++){
      s4v lo={vtmp[p][0],vtmp[p][1],vtmp[p][2],vtmp[p][3]};
      s4v hi={vtmp[p][4],vtmp[p][5],vtmp[p][6],vtmp[p][7]};
      *(s4v*)&Vs[vw0[p]]=lo;
      *(s4v*)&Vs[vw1[p]]=hi;
    }
    const int tv=((it+1)&31)*1024;
    #pragma unroll
    for(int p=0;p<4;p++) vtmp[p]=*(const s8v*)(vp[p]+tv);   // V(t+1)
    f4v e0[4];
    #pragma unroll
    for(int hh=0;hh<4;hh++){
      const unsigned short* kb=&Ks[((h0+hh)*16+row16)*64];
      f4v S={0.f,0.f,0.f,0.f};
      S=MFMA32(*(const s8v*)&kb[sw0], qf[hh][0], S);
      S=MFMA32(*(const s8v*)&kb[sw1], qf[hh][1], S);
      #pragma unroll
      for(int r=0;r<4;r++) e0[hh][r]=__builtin_amdgcn_exp2f(S[r]*EXPC);
    }
    f4v d0=(e0[0]+e0[1])+(e0[2]+e0[3]);
    dpart[qg][hg][l]=d0;
    BARRIER();   // bar-mid: dpart + Vs visible; vmem stays in flight
    // ---------------- epoch B: denom, write Ks=K(t+1), PV ------------------
    f4v s0=(dpart[qg][0][l]+dpart[qg][1][l])+(dpart[qg][2][l]+dpart[qg][3][l]);
    f4v r0;
    #pragma unroll
    for(int r=0;r<4;r++) r0[r]=__builtin_amdgcn_rcpf(s0[r]);
    #pragma unroll
    for(int p=0;p<4;p++) *(s8v*)&Ks[kw[p]] = kreg[p];       // K(t+1)
    const int tk=((it+2)&31)*1024;
    #pragma unroll
    for(int p=0;p<4;p++) kreg[p]=*(const s8v*)(kp[p]+tk);   // K(t+2)
    s4v p0[4];
    #pragma unroll
    for(int hh=0;hh<4;hh++) p0[hh]=pack4(e0[hh]*r0);
    #pragma unroll
    for(int hh=0;hh<4;hh++){
      #pragma unroll
      for(int jt=0;jt<4;jt++){
        const int vrow=((h0+hh)*64+jt*16+row16)*16;
        s4v v0=*(const s4v*)&Vs[vrow + vsw];
        o[hh][jt]=MFMA16(v0, p0[hh], o[hh][jt]);
      }
    }
    BARRIER();   // bar-end: Ks(t+1) visible; Vs/dpart reads drained
  }

  // store bf16 partial: opart[ih][b][q][h*64+j]
  #pragma unroll
  for(int hh=0;hh<4;hh++)
    #pragma unroll
    for(int jt=0;jt<4;jt++)
      *(s4v*)&opart[(size_t)((ih*2+b)*2048 + q0+row16)*1024 + (h0+hh)*64 + jt*16 + quad*4]
        = pack4(o[hh][jt]);
}

// ---------------------------------------------------------------------------
// K3: reduce the 4 i-quarter partials -> out2 bf16
// ---------------------------------------------------------------------------
__global__ __launch_bounds__(256) void reduce_o(
    const unsigned short* __restrict__ op, unsigned short* __restrict__ out2)
{
  size_t e = ((size_t)blockIdx.x*256 + threadIdx.x)*8;
  s8v a = *(const s8v*)&op[e];
  s8v b = *(const s8v*)&op[(size_t)4194304 + e];
  s8v c = *(const s8v*)&op[(size_t)2*4194304 + e];
  s8v d = *(const s8v*)&op[(size_t)3*4194304 + e];
  f4v lo, hi;
  #pragma unroll
  for(int i=0;i<4;i++)
    lo[i] = (bf2f((unsigned short)a[i])+bf2f((unsigned short)b[i]))
          + (bf2f((unsigned short)c[i])+bf2f((unsigned short)d[i]));
  #pragma unroll
  for(int i=0;i<4;i++)
    hi[i] = (bf2f((unsigned short)a[i+4])+bf2f((unsigned short)b[i+4]))
          + (bf2f((unsigned short)c[i+4])+bf2f((unsigned short)d[i+4]));
  *(s4v*)&out2[e]   = pack4(lo);
  *(s4v*)&out2[e+4] = pack4(hi);
}

// ---------------------------------------------------------------------------
// K4: res[m][n] = sum_k out2[m,k]*WoP[n,k] + bo[n], fp32 out
// ---------------------------------------------------------------------------
__global__ __launch_bounds__(256) void out_gemm(
    const unsigned short* __restrict__ A, const unsigned short* __restrict__ Bm,
    const float* __restrict__ bias, float* __restrict__ out)
{
  __shared__ short As[128*64];
  __shared__ short Bs[128*64];
  const int t=threadIdx.x, l=t&63, w=t>>6;
  const int row16=l&15, quad=l>>4;
  const int m0=blockIdx.x*128, n0=blockIdx.y*128;
  const int wm=(w>>1)*64, wn=(w&1)*64;
  f4v acc[4][4];
  #pragma unroll
  for(int i=0;i<4;i++)
    #pragma unroll
    for(int j=0;j<4;j++) acc[i][j] = (f4v){0.f,0.f,0.f,0.f};

  const int sr=t>>3, sc=(t&7)*8;
  for(int k0=0;k0<1024;k0+=64){
    #pragma unroll
    for(int p=0;p<4;p++){
      *(s8v*)&As[(p*32+sr)*64 + sc] = *(const s8v*)&A [(size_t)(m0+p*32+sr)*1024 + k0 + sc];
      *(s8v*)&Bs[(p*32+sr)*64 + sc] = *(const s8v*)&Bm[(size_t)(n0+p*32+sr)*1024 + k0 + sc];
    }
    __syncthreads();
    #pragma unroll
    for(int kk=0; kk<64; kk+=32){
      s8v af[4], bf[4];
      #pragma unroll
      for(int mt=0;mt<4;mt++) af[mt] = *(const s8v*)&As[(wm+mt*16+row16)*64 + kk + quad*8];
      #pragma unroll
      for(int nt=0;nt<4;nt++) bf[nt] = *(const s8v*)&Bs[(wn+nt*16+row16)*64 + kk + quad*8];
      #pragma unroll
      for(int mt=0;mt<4;mt++)
        #pragma unroll
        for(int nt=0;nt<4;nt++)
          acc[mt][nt] = MFMA32(af[mt], bf[nt], acc[mt][nt]);
    }
    __syncthreads();
  }
  #pragma unroll
  for(int nt=0;nt<4;nt++){
    const int n = n0+wn+nt*16+row16;
    const float bias_n = bias[n];
    #pragma unroll
    for(int mt=0;mt<4;mt++)
      #pragma unroll
      for(int r=0;r<4;r++){
        const int m = m0+wm+mt*16+quad*4+r;
        out[(size_t)m*1024 + n] = acc[mt][nt][r] + bias_n;
      }
  }
}

// ---------------------------------------------------------------------------
// Workspace (56 MiB):
//   kb    @  0 MiB   (8)  bf16 KEY      dead after proj_gemm
//   qb    @  8 MiB   (8)  bf16 QUERY    dead after proj_gemm
//   vb    @ 16 MiB   (8)  bf16 VALUE    dead after proj_gemm
//   wkb   @ 24 MiB   (2)  bf16 Wk       dead after proj_gemm
//   wqb   @ 26 MiB   (2)  bf16 Wq       dead after proj_gemm
//   wvb   @ 28 MiB   (2)  bf16 Wv       dead after proj_gemm
//   kh    @ 32 MiB   (8)  dead after fused_attn
//   qh    @ 40 MiB   (8)  dead after fused_attn
//   vt    @ 48 MiB   (8)  dead after fused_attn
//   opart @  0 MiB   (32) overlaps dead kb..wvb  [4ih][2b][2048][1024]
//   wop   @ 32 MiB   (2)  overlaps dead kh (pack_wo after fused_attn)
//   out2  @ 34 MiB   (8)  overlaps dead kh/qh
// ---------------------------------------------------------------------------
extern "C" void kernel_launch(void* const* d_in, const int* in_sizes, int n_in,
                              void* d_out, int out_size, void* d_ws, size_t ws_size,
                              hipStream_t stream)
{
  const float* KEY   = (const float*)d_in[0];
  const float* VALUE = (const float*)d_in[1];
  const float* QUERY = (const float*)d_in[2];
  const float* Wk = (const float*)d_in[3];
  const float* bk = (const float*)d_in[4];
  const float* Wq = (const float*)d_in[5];
  const float* bq = (const float*)d_in[6];
  const float* Wv = (const float*)d_in[7];
  const float* bv = (const float*)d_in[8];
  const float* Wo = (const float*)d_in[9];
  const float* bo = (const float*)d_in[10];

  char* ws = (char*)d_ws;
  unsigned short* kb   = (unsigned short*)(ws);
  unsigned short* qb   = (unsigned short*)(ws +  8388608);
  unsigned short* vb   = (unsigned short*)(ws + 16777216);
  unsigned short* wkb  = (unsigned short*)(ws + 25165824);
  unsigned short* wqb  = (unsigned short*)(ws + 27262976);
  unsigned short* wvb  = (unsigned short*)(ws + 29360128);
  unsigned short* kh   = (unsigned short*)(ws + 33554432);
  unsigned short* qh   = (unsigned short*)(ws + 41943040);
  unsigned short* vt   = (unsigned short*)(ws + 50331648);
  unsigned short* opart= (unsigned short*)(ws);             // overlap kb..wvb
  unsigned short* wop  = (unsigned short*)(ws + 33554432);  // overlap kh
  unsigned short* out2 = (unsigned short*)(ws + 35651584);  // overlap kh/qh

  conv_in   <<<dim3(2048,6), dim3(256), 0, stream>>>(KEY,QUERY,VALUE,Wk,Wq,Wv,kb,qb,vb,wkb,wqb,wvb);
  proj_gemm <<<dim3(32,8,3), dim3(256), 0, stream>>>(kb,qb,vb,wkb,wqb,wvb,bk,bq,bv,kh,qh,vt);
  fused_attn<<<dim3(512),    dim3(512), 0, stream>>>(kh,qh,vt,opart);
  pack_wo   <<<dim3(4096),   dim3(256), 0, stream>>>(Wo,wop);
  reduce_o  <<<dim3(2048),   dim3(256), 0, stream>>>(opart,out2);
  out_gemm  <<<dim3(32,8),   dim3(256), 0, stream>>>(out2,wop,bo,(float*)d_out);
}